// Round 1
// 240.626 us; speedup vs baseline: 1.0133x; 1.0133x over previous
//
#include <hip/hip_runtime.h>
#include <hip/hip_fp16.h>

#define NNODES 100000
#define NB 196         // coarse buckets: node >> 9 (512 nodes each)
#define BSHIFT 9
#define BMASK 511
#define BCAP 9216      // per-bucket capacity (avg 8163, sigma ~90 -> +11.7 sigma)
#define WT_LD 136      // padded k-stride (halves) for transposed W1

typedef _Float16 half8 __attribute__((ext_vector_type(8)));
typedef float floatx4 __attribute__((ext_vector_type(4)));

// ---- phase A: coarse-bin edges; two LDS atomics/edge (R11-proven shape) ----
__global__ void binA_kernel(const int* __restrict__ src, const int* __restrict__ dst,
                            int* __restrict__ bcnt, unsigned* __restrict__ bdata, int E) {
    __shared__ int hist[NB];
    __shared__ int gb[NB];
    __shared__ int cur[NB];
    const int BATCH = 4096;  // 16 edges / thread
    for (int base = blockIdx.x * BATCH; base < E; base += gridDim.x * BATCH) {
        for (int i = threadIdx.x; i < NB; i += blockDim.x) hist[i] = 0;
        __syncthreads();
        int s[16], d[16];
        int cnt = 0;
        if (base + BATCH <= E) {  // full batch: int4 loads
#pragma unroll
            for (int q = 0; q < 4; ++q) {
                int4 sv = ((const int4*)(src + base))[q * 256 + threadIdx.x];
                int4 dv = ((const int4*)(dst + base))[q * 256 + threadIdx.x];
                s[cnt] = sv.x; d[cnt] = dv.x; atomicAdd(&hist[dv.x >> BSHIFT], 1); ++cnt;
                s[cnt] = sv.y; d[cnt] = dv.y; atomicAdd(&hist[dv.y >> BSHIFT], 1); ++cnt;
                s[cnt] = sv.z; d[cnt] = dv.z; atomicAdd(&hist[dv.z >> BSHIFT], 1); ++cnt;
                s[cnt] = sv.w; d[cnt] = dv.w; atomicAdd(&hist[dv.w >> BSHIFT], 1); ++cnt;
            }
        } else {
#pragma unroll
            for (int k = 0; k < 16; ++k) {
                int idx = base + k * 256 + threadIdx.x;
                if (idx < E) {
                    s[cnt] = src[idx];
                    d[cnt] = dst[idx];
                    atomicAdd(&hist[d[cnt] >> BSHIFT], 1);
                    ++cnt;
                }
            }
        }
        __syncthreads();
        for (int i = threadIdx.x; i < NB; i += blockDim.x) {
            int c = hist[i];
            gb[i] = (c > 0) ? atomicAdd(&bcnt[i], c) : 0;
            cur[i] = 0;
        }
        __syncthreads();
        for (int k = 0; k < cnt; ++k) {
            int b = d[k] >> BSHIFT;
            int lo = gb[b] + atomicAdd(&cur[b], 1);
            if (lo < BCAP)
                bdata[(size_t)b * BCAP + lo] = ((unsigned)s[k] << BSHIFT) | ((unsigned)d[k] & BMASK);
        }
        __syncthreads();
    }
}

// ---- fused prep: block 0 = bucket scan, block 1 = w23 fold, block 2 = W1 transpose/fp16 ----
__global__ __launch_bounds__(1024) void prep_kernel(
        const int* __restrict__ bcnt, int* __restrict__ bstart,
        const float* __restrict__ W2, const float* __restrict__ b2,
        const float* __restrict__ W3, float* __restrict__ w23,
        const float* __restrict__ W1, __half* __restrict__ Wt) {
    if (blockIdx.x == 0) {
        __shared__ int sh[NB];
        int t = threadIdx.x;
        if (t < NB) sh[t] = min(bcnt[t], BCAP);
        __syncthreads();
        if (t == 0) {
            int acc = 0;
            for (int i = 0; i < NB; ++i) { int v = sh[i]; sh[i] = acc; acc += v; }
        }
        __syncthreads();
        if (t < NB) bstart[t] = sh[t];
    } else if (blockIdx.x == 1) {
        int k = threadIdx.x;
        if (k < 71) {
            float a = 0.f;
            for (int j = 0; j < 82; ++j) a += W2[k * 82 + j] * W3[j];
            w23[k] = a;
        } else if (k == 71) {
            float a = 0.f;
            for (int j = 0; j < 82; ++j) a += b2[j] * W3[j];
            w23[71] = a;
        }
    } else {
        for (int i = threadIdx.x; i < 80 * WT_LD; i += blockDim.x) {
            int nn = i / WT_LD, k = i - nn * WT_LD;
            float v = (nn < 71 && k < 128) ? W1[k * 71 + nn] : 0.f;
            Wt[i] = __float2half(v);
        }
    }
}

// ---- phase B: per-bucket (512 nodes) LDS-cached hist + scan + CSR fill (R11 shape) ----
__global__ __launch_bounds__(1024) void binB2_kernel(
        const int* __restrict__ bcnt, const int* __restrict__ bstart,
        const unsigned* __restrict__ bdata,
        int* __restrict__ deg, int* __restrict__ end_off, float* __restrict__ dinv,
        int* __restrict__ csr, int n) {
    __shared__ unsigned edata[BCAP];   // 36 KB: bucket cached in LDS
    __shared__ int hist[512];
    __shared__ int cur[512];
    __shared__ int wsum[8];
    int b = blockIdx.x;
    int tid = threadIdx.x;
    int cnt = min(bcnt[b], BCAP);
    int base = bstart[b];
    const unsigned* p = bdata + (size_t)b * BCAP;
    if (tid < 512) hist[tid] = 0;
    __syncthreads();
    for (int i = tid; i < cnt; i += 1024) {
        unsigned e = p[i];
        edata[i] = e;
        atomicAdd(&hist[e & BMASK], 1);
    }
    __syncthreads();
    if (tid < 512) {  // 8-wave inclusive scan of hist
        int v = hist[tid];
        int lane = tid & 63;
        int incl = v;
#pragma unroll
        for (int off = 1; off < 64; off <<= 1) {
            int t = __shfl_up(incl, off);
            if (lane >= off) incl += t;
        }
        cur[tid] = incl;  // stash inclusive intra-wave prefix
        if (lane == 63) wsum[tid >> 6] = incl;
    }
    __syncthreads();
    if (tid == 0) {
        int acc = 0;
#pragma unroll
        for (int w = 0; w < 8; ++w) { int t = wsum[w]; wsum[w] = acc; acc += t; }
    }
    __syncthreads();
    if (tid < 512) {
        int v = hist[tid];
        int start = base + wsum[tid >> 6] + cur[tid] - v;  // exclusive prefix
        int node = (b << BSHIFT) + tid;
        if (node < n) {
            deg[node] = v;
            end_off[node] = start + v;
            dinv[node] = rsqrtf((float)v + 1.0f);
        }
        cur[tid] = start;
    }
    __syncthreads();
    for (int i = tid; i < cnt; i += 1024) {
        unsigned e = edata[i];
        int pos = atomicAdd(&cur[e & BMASK], 1);
        csr[pos] = (int)(e >> BSHIFT);
    }
}

// ---- MFMA transform: msg[row, 0..71] = half( (x[row,:128] @ W1) * scale[row] ) ----
__global__ __launch_bounds__(256) void xform_mfma(
        const float* __restrict__ x, const __half* __restrict__ Wt,
        const float* __restrict__ scale, __half* __restrict__ msg, int n) {
    __shared__ __half Wsh[80 * WT_LD];   // 21.25 KB
    {
        const uint4* sp = (const uint4*)Wt;
        uint4* dp = (uint4*)Wsh;
        for (int i = threadIdx.x; i < (80 * WT_LD * 2) / 16; i += blockDim.x) dp[i] = sp[i];
    }
    __syncthreads();
    int lane = threadIdx.x & 63;
    int m = lane & 15, q = lane >> 4;
    int gw = (blockIdx.x * blockDim.x + threadIdx.x) >> 6;
    int nw = (gridDim.x * blockDim.x) >> 6;
    int nrt = n >> 4;  // 16-row tiles (n % 16 == 0)
    for (int rt = gw; rt < nrt; rt += nw) {
        int rb = rt << 4;
        const float* xr = x + (size_t)(rb + m) * 128 + q * 8;
        floatx4 acc[5];
#pragma unroll
        for (int t = 0; t < 5; ++t) acc[t] = (floatx4){0.f, 0.f, 0.f, 0.f};
#pragma unroll
        for (int ks = 0; ks < 4; ++ks) {
            float4 f0 = *(const float4*)(xr + ks * 32);
            float4 f1 = *(const float4*)(xr + ks * 32 + 4);
            half8 a;
            a[0] = (_Float16)f0.x; a[1] = (_Float16)f0.y;
            a[2] = (_Float16)f0.z; a[3] = (_Float16)f0.w;
            a[4] = (_Float16)f1.x; a[5] = (_Float16)f1.y;
            a[6] = (_Float16)f1.z; a[7] = (_Float16)f1.w;
#pragma unroll
            for (int t = 0; t < 5; ++t) {
                half8 b = *(const half8*)&Wsh[(t * 16 + m) * WT_LD + ks * 32 + q * 8];
                acc[t] = __builtin_amdgcn_mfma_f32_16x16x32_f16(a, b, acc[t], 0, 0, 0);
            }
        }
        float sc[4];
#pragma unroll
        for (int r = 0; r < 4; ++r) sc[r] = scale[rb + q * 4 + r];
#pragma unroll
        for (int t = 0; t < 5; ++t) {
            int col = t * 16 + m;
            if (col < 72) {
#pragma unroll
                for (int r = 0; r < 4; ++r)
                    msg[(size_t)(rb + q * 4 + r) * 72 + col] = __float2half(acc[t][r] * sc[r]);
            }
        }
    }
}

// ---- fused gather + ReLU + w23 contraction: wave per node ----
// R12: readlane (SGPR broadcast) -> scalar row base -> saddr-form gathers;
// address math moves VALU -> SALU; 16 independent loads in flight.
template <int OC>
__global__ void gather_fused(const __half2* __restrict__ msg, const int* __restrict__ csr,
                             const int* __restrict__ end_off, const int* __restrict__ deg,
                             const float* __restrict__ dinv, const float* __restrict__ b,
                             const float* __restrict__ w23, float* __restrict__ g2, int n) {
    constexpr int OC2 = (OC + 1) / 2;
    int lane = threadIdx.x & 63;
    int wid = (blockIdx.x * blockDim.x + threadIdx.x) >> 6;
    int nwaves = (gridDim.x * blockDim.x) >> 6;
    bool act = lane < OC2;
    int c = lane << 1;
    float bx = (act && c < OC) ? b[c] : 0.f;
    float by = (act && c + 1 < OC) ? b[c + 1] : 0.f;
    float w0 = (act && c < OC) ? w23[c] : 0.f;
    float w1 = (act && c + 1 < OC) ? w23[c + 1] : 0.f;
    for (int node = wid; node < n; node += nwaves) {
        int end = end_off[node];
        int cnt = deg[node];
        int start = end - cnt;
        float ax0 = 0.f, ay0 = 0.f, ax1 = 0.f, ay1 = 0.f;
        float ax2 = 0.f, ay2 = 0.f, ax3 = 0.f, ay3 = 0.f;
        for (int base = 0; base < cnt; base += 64) {
            int rem = min(cnt - base, 64);
            int se = (lane < rem) ? csr[start + base + lane] : 0;
            int j = 0;
            for (; j + 15 < rem; j += 16) {
                int s0  = __builtin_amdgcn_readlane(se, j + 0);
                int s1  = __builtin_amdgcn_readlane(se, j + 1);
                int s2  = __builtin_amdgcn_readlane(se, j + 2);
                int s3  = __builtin_amdgcn_readlane(se, j + 3);
                int s4  = __builtin_amdgcn_readlane(se, j + 4);
                int s5  = __builtin_amdgcn_readlane(se, j + 5);
                int s6  = __builtin_amdgcn_readlane(se, j + 6);
                int s7  = __builtin_amdgcn_readlane(se, j + 7);
                int s8  = __builtin_amdgcn_readlane(se, j + 8);
                int s9  = __builtin_amdgcn_readlane(se, j + 9);
                int s10 = __builtin_amdgcn_readlane(se, j + 10);
                int s11 = __builtin_amdgcn_readlane(se, j + 11);
                int s12 = __builtin_amdgcn_readlane(se, j + 12);
                int s13 = __builtin_amdgcn_readlane(se, j + 13);
                int s14 = __builtin_amdgcn_readlane(se, j + 14);
                int s15 = __builtin_amdgcn_readlane(se, j + 15);
                if (act) {
                    float2 v0  = __half22float2(msg[(size_t)s0  * OC2 + lane]);
                    float2 v1  = __half22float2(msg[(size_t)s1  * OC2 + lane]);
                    float2 v2  = __half22float2(msg[(size_t)s2  * OC2 + lane]);
                    float2 v3  = __half22float2(msg[(size_t)s3  * OC2 + lane]);
                    float2 v4  = __half22float2(msg[(size_t)s4  * OC2 + lane]);
                    float2 v5  = __half22float2(msg[(size_t)s5  * OC2 + lane]);
                    float2 v6  = __half22float2(msg[(size_t)s6  * OC2 + lane]);
                    float2 v7  = __half22float2(msg[(size_t)s7  * OC2 + lane]);
                    float2 v8  = __half22float2(msg[(size_t)s8  * OC2 + lane]);
                    float2 v9  = __half22float2(msg[(size_t)s9  * OC2 + lane]);
                    float2 v10 = __half22float2(msg[(size_t)s10 * OC2 + lane]);
                    float2 v11 = __half22float2(msg[(size_t)s11 * OC2 + lane]);
                    float2 v12 = __half22float2(msg[(size_t)s12 * OC2 + lane]);
                    float2 v13 = __half22float2(msg[(size_t)s13 * OC2 + lane]);
                    float2 v14 = __half22float2(msg[(size_t)s14 * OC2 + lane]);
                    float2 v15 = __half22float2(msg[(size_t)s15 * OC2 + lane]);
                    ax0 += v0.x;  ay0 += v0.y;   ax1 += v1.x;  ay1 += v1.y;
                    ax2 += v2.x;  ay2 += v2.y;   ax3 += v3.x;  ay3 += v3.y;
                    ax0 += v4.x;  ay0 += v4.y;   ax1 += v5.x;  ay1 += v5.y;
                    ax2 += v6.x;  ay2 += v6.y;   ax3 += v7.x;  ay3 += v7.y;
                    ax0 += v8.x;  ay0 += v8.y;   ax1 += v9.x;  ay1 += v9.y;
                    ax2 += v10.x; ay2 += v10.y;  ax3 += v11.x; ay3 += v11.y;
                    ax0 += v12.x; ay0 += v12.y;  ax1 += v13.x; ay1 += v13.y;
                    ax2 += v14.x; ay2 += v14.y;  ax3 += v15.x; ay3 += v15.y;
                }
            }
            for (; j + 7 < rem; j += 8) {
                int s0 = __builtin_amdgcn_readlane(se, j + 0);
                int s1 = __builtin_amdgcn_readlane(se, j + 1);
                int s2 = __builtin_amdgcn_readlane(se, j + 2);
                int s3 = __builtin_amdgcn_readlane(se, j + 3);
                int s4 = __builtin_amdgcn_readlane(se, j + 4);
                int s5 = __builtin_amdgcn_readlane(se, j + 5);
                int s6 = __builtin_amdgcn_readlane(se, j + 6);
                int s7 = __builtin_amdgcn_readlane(se, j + 7);
                if (act) {
                    float2 v0 = __half22float2(msg[(size_t)s0 * OC2 + lane]);
                    float2 v1 = __half22float2(msg[(size_t)s1 * OC2 + lane]);
                    float2 v2 = __half22float2(msg[(size_t)s2 * OC2 + lane]);
                    float2 v3 = __half22float2(msg[(size_t)s3 * OC2 + lane]);
                    float2 v4 = __half22float2(msg[(size_t)s4 * OC2 + lane]);
                    float2 v5 = __half22float2(msg[(size_t)s5 * OC2 + lane]);
                    float2 v6 = __half22float2(msg[(size_t)s6 * OC2 + lane]);
                    float2 v7 = __half22float2(msg[(size_t)s7 * OC2 + lane]);
                    ax0 += v0.x; ay0 += v0.y;  ax1 += v1.x; ay1 += v1.y;
                    ax2 += v2.x; ay2 += v2.y;  ax3 += v3.x; ay3 += v3.y;
                    ax0 += v4.x; ay0 += v4.y;  ax1 += v5.x; ay1 += v5.y;
                    ax2 += v6.x; ay2 += v6.y;  ax3 += v7.x; ay3 += v7.y;
                }
            }
            for (; j + 3 < rem; j += 4) {
                int s0 = __builtin_amdgcn_readlane(se, j + 0);
                int s1 = __builtin_amdgcn_readlane(se, j + 1);
                int s2 = __builtin_amdgcn_readlane(se, j + 2);
                int s3 = __builtin_amdgcn_readlane(se, j + 3);
                if (act) {
                    float2 v0 = __half22float2(msg[(size_t)s0 * OC2 + lane]);
                    float2 v1 = __half22float2(msg[(size_t)s1 * OC2 + lane]);
                    float2 v2 = __half22float2(msg[(size_t)s2 * OC2 + lane]);
                    float2 v3 = __half22float2(msg[(size_t)s3 * OC2 + lane]);
                    ax0 += v0.x; ay0 += v0.y;  ax1 += v1.x; ay1 += v1.y;
                    ax2 += v2.x; ay2 += v2.y;  ax3 += v3.x; ay3 += v3.y;
                }
            }
            for (; j < rem; ++j) {
                int s = __builtin_amdgcn_readlane(se, j);
                if (act) {
                    float2 v = __half22float2(msg[(size_t)s * OC2 + lane]);
                    ax0 += v.x; ay0 += v.y;
                }
            }
        }
        float dv = dinv[node];
        float p = 0.f;
        if (act) {
            float2 selfv = __half22float2(msg[(size_t)node * OC2 + lane]);
            float sx = ((ax0 + ax1) + (ax2 + ax3)) + selfv.x;
            float sy = ((ay0 + ay1) + (ay2 + ay3)) + selfv.y;
            float vx = fmaxf(dv * sx + bx, 0.f);   // ReLU
            float vy = fmaxf(dv * sy + by, 0.f);
            p = vx * w0 + vy * w1;
        }
#pragma unroll
        for (int off = 32; off > 0; off >>= 1) p += __shfl_down(p, off);
        if (lane == 0) g2[node] = dv * p;
    }
}

// ---- scalar gather 1: q[i] = dinv_i * ( dinv_i*(sum g2[src] + g2[i]) + bw ) ----
// R12: 16-lane group per node (was thread-per-node): coalesced csr, parallel g2 gathers.
__global__ void sgather_q(const float* __restrict__ g2, const int* __restrict__ csr,
                          const int* __restrict__ end_off, const int* __restrict__ deg,
                          const float* __restrict__ dinv, const float* __restrict__ w23,
                          float* __restrict__ q, int n) {
    float bw = w23[71];
    int lane = threadIdx.x & 63;
    int g = lane >> 4, k = lane & 15;
    int wid = (blockIdx.x * blockDim.x + threadIdx.x) >> 6;
    int nw = (gridDim.x * blockDim.x) >> 6;
    for (int i0 = wid * 4; i0 < n; i0 += nw * 4) {
        int i = i0 + g;
        float acc = 0.f;
        float dv = 0.f;
        if (i < n) {
            int end = end_off[i];
            int cnt = deg[i];
            int start = end - cnt;
            dv = dinv[i];
            for (int e = k; e < cnt; e += 16) acc += g2[csr[start + e]];
        }
        acc += __shfl_down(acc, 8, 16);
        acc += __shfl_down(acc, 4, 16);
        acc += __shfl_down(acc, 2, 16);
        acc += __shfl_down(acc, 1, 16);
        if (i < n && k == 0) q[i] = dv * (dv * (acc + g2[i]) + bw);
    }
}

// ---- scalar gather 2: out[i] = dinv_i*(sum q[src] + q[i]) + b3 ----
__global__ void sgather_out(const float* __restrict__ q, const int* __restrict__ csr,
                            const int* __restrict__ end_off, const int* __restrict__ deg,
                            const float* __restrict__ dinv, const float* __restrict__ b3,
                            float* __restrict__ out, int n) {
    float bv = b3[0];
    int lane = threadIdx.x & 63;
    int g = lane >> 4, k = lane & 15;
    int wid = (blockIdx.x * blockDim.x + threadIdx.x) >> 6;
    int nw = (gridDim.x * blockDim.x) >> 6;
    for (int i0 = wid * 4; i0 < n; i0 += nw * 4) {
        int i = i0 + g;
        float acc = 0.f;
        float dv = 0.f;
        if (i < n) {
            int end = end_off[i];
            int cnt = deg[i];
            int start = end - cnt;
            dv = dinv[i];
            for (int e = k; e < cnt; e += 16) acc += q[csr[start + e]];
        }
        acc += __shfl_down(acc, 8, 16);
        acc += __shfl_down(acc, 4, 16);
        acc += __shfl_down(acc, 2, 16);
        acc += __shfl_down(acc, 1, 16);
        if (i < n && k == 0) out[i] = dv * (acc + q[i]) + bv;
    }
}

extern "C" void kernel_launch(void* const* d_in, const int* in_sizes, int n_in,
                              void* d_out, int out_size, void* d_ws, size_t ws_size,
                              hipStream_t stream) {
    const float* x  = (const float*)d_in[0];
    const int*   ei = (const int*)d_in[1];
    const float* W1 = (const float*)d_in[2];
    const float* b1 = (const float*)d_in[3];
    const float* W2 = (const float*)d_in[4];
    const float* b2 = (const float*)d_in[5];
    const float* W3 = (const float*)d_in[6];
    const float* b3 = (const float*)d_in[7];
    float* out = (float*)d_out;

    const int n = NNODES;
    const int E = in_sizes[1] / 2;
    const int* src = ei;
    const int* dst = ei + E;

    float* ws     = (float*)d_ws;
    float* dinv   = ws;                        // n f32
    int*   deg_i  = (int*)(ws + n);            // n i32
    int*   offs   = deg_i + n;                 // n i32 (END offsets)
    int*   bcnt   = offs + n;                  // 256 i32
    int*   bstart = bcnt + 256;                // 256 i32
    float* w23    = (float*)(bstart + 256);    // 72 f32 (+ pad to 80)
    __half* Wt    = (__half*)(w23 + 80);       // 80*WT_LD halves (pad to 11008)
    float* g2     = (float*)(Wt + 11008);      // n f32
    float* q      = g2 + n;                    // n f32
    int*   csr    = (int*)(q + n);             // E i32
    __half* msg   = (__half*)(csr + E);        // n*72 halves (14.4 MB)
    unsigned* bdata = (unsigned*)(msg + (size_t)n * 72);  // NB*BCAP u32 (7.2 MB)

    // ---- CSR build ----
    hipMemsetAsync(bcnt, 0, 256 * sizeof(int), stream);
    binA_kernel<<<(E + 4095) / 4096, 256, 0, stream>>>(src, dst, bcnt, bdata, E);
    prep_kernel<<<3, 1024, 0, stream>>>(bcnt, bstart, W2, b2, W3, w23, W1, Wt);
    binB2_kernel<<<NB, 1024, 0, stream>>>(bcnt, bstart, bdata, deg_i, offs, dinv, csr, n);

    // ---- layer 1 transform via MFMA: msg = fp16( (x@W1)*dinv ) ----
    xform_mfma<<<1563, 256, 0, stream>>>(x, Wt, dinv, msg, n);

    // ---- fused layer-1 gather + ReLU + (W2*W3) contraction -> scalar per node ----
    gather_fused<71><<<2048, 256, 0, stream>>>((const __half2*)msg, csr, offs, deg_i, dinv, b1, w23, g2, n);

    // ---- collapsed layers 2+3: two scalar aggregations (16-lane group per node) ----
    sgather_q<<<1024, 256, 0, stream>>>(g2, csr, offs, deg_i, dinv, w23, q, n);
    sgather_out<<<1024, 256, 0, stream>>>(q, csr, offs, deg_i, dinv, b3, out, n);
}

// Round 2
// 238.905 us; speedup vs baseline: 1.0206x; 1.0072x over previous
//
#include <hip/hip_runtime.h>
#include <hip/hip_fp16.h>

#define NNODES 100000
#define NB 196         // coarse buckets: node >> 9 (512 nodes each)
#define BSHIFT 9
#define BMASK 511
#define BCAP 9216      // per-bucket capacity (avg 8163, sigma ~90 -> +11.7 sigma)
#define WT_LD 136      // padded k-stride (halves) for transposed W1

typedef _Float16 half8 __attribute__((ext_vector_type(8)));
typedef float floatx4 __attribute__((ext_vector_type(4)));

// ---- phase A: coarse-bin edges; two LDS atomics/edge (R11-proven shape) ----
__global__ void binA_kernel(const int* __restrict__ src, const int* __restrict__ dst,
                            int* __restrict__ bcnt, unsigned* __restrict__ bdata, int E) {
    __shared__ int hist[NB];
    __shared__ int gb[NB];
    __shared__ int cur[NB];
    const int BATCH = 4096;  // 16 edges / thread
    for (int base = blockIdx.x * BATCH; base < E; base += gridDim.x * BATCH) {
        for (int i = threadIdx.x; i < NB; i += blockDim.x) hist[i] = 0;
        __syncthreads();
        int s[16], d[16];
        int cnt = 0;
        if (base + BATCH <= E) {  // full batch: int4 loads
#pragma unroll
            for (int q = 0; q < 4; ++q) {
                int4 sv = ((const int4*)(src + base))[q * 256 + threadIdx.x];
                int4 dv = ((const int4*)(dst + base))[q * 256 + threadIdx.x];
                s[cnt] = sv.x; d[cnt] = dv.x; atomicAdd(&hist[dv.x >> BSHIFT], 1); ++cnt;
                s[cnt] = sv.y; d[cnt] = dv.y; atomicAdd(&hist[dv.y >> BSHIFT], 1); ++cnt;
                s[cnt] = sv.z; d[cnt] = dv.z; atomicAdd(&hist[dv.z >> BSHIFT], 1); ++cnt;
                s[cnt] = sv.w; d[cnt] = dv.w; atomicAdd(&hist[dv.w >> BSHIFT], 1); ++cnt;
            }
        } else {
#pragma unroll
            for (int k = 0; k < 16; ++k) {
                int idx = base + k * 256 + threadIdx.x;
                if (idx < E) {
                    s[cnt] = src[idx];
                    d[cnt] = dst[idx];
                    atomicAdd(&hist[d[cnt] >> BSHIFT], 1);
                    ++cnt;
                }
            }
        }
        __syncthreads();
        for (int i = threadIdx.x; i < NB; i += blockDim.x) {
            int c = hist[i];
            gb[i] = (c > 0) ? atomicAdd(&bcnt[i], c) : 0;
            cur[i] = 0;
        }
        __syncthreads();
        for (int k = 0; k < cnt; ++k) {
            int b = d[k] >> BSHIFT;
            int lo = gb[b] + atomicAdd(&cur[b], 1);
            if (lo < BCAP)
                bdata[(size_t)b * BCAP + lo] = ((unsigned)s[k] << BSHIFT) | ((unsigned)d[k] & BMASK);
        }
        __syncthreads();
    }
}

// ---- fused prep: block 0 = bucket scan, block 1 = w23 fold, block 2 = W1 transpose/fp16 ----
__global__ __launch_bounds__(1024) void prep_kernel(
        const int* __restrict__ bcnt, int* __restrict__ bstart,
        const float* __restrict__ W2, const float* __restrict__ b2,
        const float* __restrict__ W3, float* __restrict__ w23,
        const float* __restrict__ W1, __half* __restrict__ Wt) {
    if (blockIdx.x == 0) {
        __shared__ int sh[NB];
        int t = threadIdx.x;
        if (t < NB) sh[t] = min(bcnt[t], BCAP);
        __syncthreads();
        if (t == 0) {
            int acc = 0;
            for (int i = 0; i < NB; ++i) { int v = sh[i]; sh[i] = acc; acc += v; }
        }
        __syncthreads();
        if (t < NB) bstart[t] = sh[t];
    } else if (blockIdx.x == 1) {
        int k = threadIdx.x;
        if (k < 71) {
            float a = 0.f;
            for (int j = 0; j < 82; ++j) a += W2[k * 82 + j] * W3[j];
            w23[k] = a;
        } else if (k == 71) {
            float a = 0.f;
            for (int j = 0; j < 82; ++j) a += b2[j] * W3[j];
            w23[71] = a;
        }
    } else {
        for (int i = threadIdx.x; i < 80 * WT_LD; i += blockDim.x) {
            int nn = i / WT_LD, k = i - nn * WT_LD;
            float v = (nn < 71 && k < 128) ? W1[k * 71 + nn] : 0.f;
            Wt[i] = __float2half(v);
        }
    }
}

// ---- phase B: per-bucket (512 nodes) LDS-cached hist + scan + CSR fill (R11 shape) ----
__global__ __launch_bounds__(1024) void binB2_kernel(
        const int* __restrict__ bcnt, const int* __restrict__ bstart,
        const unsigned* __restrict__ bdata,
        int* __restrict__ deg, int* __restrict__ end_off, float* __restrict__ dinv,
        int* __restrict__ csr, int n) {
    __shared__ unsigned edata[BCAP];   // 36 KB: bucket cached in LDS
    __shared__ int hist[512];
    __shared__ int cur[512];
    __shared__ int wsum[8];
    int b = blockIdx.x;
    int tid = threadIdx.x;
    int cnt = min(bcnt[b], BCAP);
    int base = bstart[b];
    const unsigned* p = bdata + (size_t)b * BCAP;
    if (tid < 512) hist[tid] = 0;
    __syncthreads();
    for (int i = tid; i < cnt; i += 1024) {
        unsigned e = p[i];
        edata[i] = e;
        atomicAdd(&hist[e & BMASK], 1);
    }
    __syncthreads();
    if (tid < 512) {  // 8-wave inclusive scan of hist
        int v = hist[tid];
        int lane = tid & 63;
        int incl = v;
#pragma unroll
        for (int off = 1; off < 64; off <<= 1) {
            int t = __shfl_up(incl, off);
            if (lane >= off) incl += t;
        }
        cur[tid] = incl;  // stash inclusive intra-wave prefix
        if (lane == 63) wsum[tid >> 6] = incl;
    }
    __syncthreads();
    if (tid == 0) {
        int acc = 0;
#pragma unroll
        for (int w = 0; w < 8; ++w) { int t = wsum[w]; wsum[w] = acc; acc += t; }
    }
    __syncthreads();
    if (tid < 512) {
        int v = hist[tid];
        int start = base + wsum[tid >> 6] + cur[tid] - v;  // exclusive prefix
        int node = (b << BSHIFT) + tid;
        if (node < n) {
            deg[node] = v;
            end_off[node] = start + v;
            dinv[node] = rsqrtf((float)v + 1.0f);
        }
        cur[tid] = start;
    }
    __syncthreads();
    for (int i = tid; i < cnt; i += 1024) {
        unsigned e = edata[i];
        int pos = atomicAdd(&cur[e & BMASK], 1);
        csr[pos] = (int)(e >> BSHIFT);
    }
}

// ---- MFMA transform: split-channel output ----
// msgA[row][0..63] (128B rows, 2 aligned lines), msgB[row][0..7] (chs 64..71, 16B rows)
__global__ __launch_bounds__(256) void xform_mfma(
        const float* __restrict__ x, const __half* __restrict__ Wt,
        const float* __restrict__ scale, __half* __restrict__ msgA,
        __half* __restrict__ msgB, int n) {
    __shared__ __half Wsh[80 * WT_LD];   // 21.25 KB
    {
        const uint4* sp = (const uint4*)Wt;
        uint4* dp = (uint4*)Wsh;
        for (int i = threadIdx.x; i < (80 * WT_LD * 2) / 16; i += blockDim.x) dp[i] = sp[i];
    }
    __syncthreads();
    int lane = threadIdx.x & 63;
    int m = lane & 15, q = lane >> 4;
    int gw = (blockIdx.x * blockDim.x + threadIdx.x) >> 6;
    int nw = (gridDim.x * blockDim.x) >> 6;
    int nrt = n >> 4;  // 16-row tiles (n % 16 == 0)
    for (int rt = gw; rt < nrt; rt += nw) {
        int rb = rt << 4;
        const float* xr = x + (size_t)(rb + m) * 128 + q * 8;
        floatx4 acc[5];
#pragma unroll
        for (int t = 0; t < 5; ++t) acc[t] = (floatx4){0.f, 0.f, 0.f, 0.f};
#pragma unroll
        for (int ks = 0; ks < 4; ++ks) {
            float4 f0 = *(const float4*)(xr + ks * 32);
            float4 f1 = *(const float4*)(xr + ks * 32 + 4);
            half8 a;
            a[0] = (_Float16)f0.x; a[1] = (_Float16)f0.y;
            a[2] = (_Float16)f0.z; a[3] = (_Float16)f0.w;
            a[4] = (_Float16)f1.x; a[5] = (_Float16)f1.y;
            a[6] = (_Float16)f1.z; a[7] = (_Float16)f1.w;
#pragma unroll
            for (int t = 0; t < 5; ++t) {
                half8 b = *(const half8*)&Wsh[(t * 16 + m) * WT_LD + ks * 32 + q * 8];
                acc[t] = __builtin_amdgcn_mfma_f32_16x16x32_f16(a, b, acc[t], 0, 0, 0);
            }
        }
        float sc[4];
#pragma unroll
        for (int r = 0; r < 4; ++r) sc[r] = scale[rb + q * 4 + r];
#pragma unroll
        for (int t = 0; t < 5; ++t) {
            int col = t * 16 + m;
#pragma unroll
            for (int r = 0; r < 4; ++r) {
                __half hv = __float2half(acc[t][r] * sc[r]);
                int row = rb + q * 4 + r;
                if (t < 4) {
                    msgA[(size_t)row * 64 + col] = hv;
                } else if (m < 8) {
                    msgB[(size_t)row * 8 + m] = hv;   // channels 64..71 (71 = zero pad)
                }
            }
        }
    }
}

// ---- fused gather + ReLU + w23 contraction: wave per node, split-channel ----
// R13: msgA 128B rows -> 2 edges per wave-load (lanes 0-31 / 32-63), 2 lines/edge;
// msgB (chs 64-70, 1.6MB, L2-resident) 16 edges per load via bpermute.
__global__ __launch_bounds__(256) void gather_fused(
        const __half2* __restrict__ msgA, const __half2* __restrict__ msgB,
        const int* __restrict__ csr, const int* __restrict__ end_off,
        const int* __restrict__ deg, const float* __restrict__ dinv,
        const float* __restrict__ b, const float* __restrict__ w23,
        float* __restrict__ g2, int n) {
    int lane = threadIdx.x & 63;
    int wid = (blockIdx.x * blockDim.x + threadIdx.x) >> 6;
    int nwaves = (gridDim.x * blockDim.x) >> 6;
    int k = lane & 31;          // A channel pair: channels (2k, 2k+1), all < 64 valid
    int c = k << 1;
    float bxA = b[c], byA = b[c + 1];
    float w0A = w23[c], w1A = w23[c + 1];
    int p = lane & 3;           // B channel pair: channels (64+2p, 65+2p)
    int cb = 64 + (p << 1);
    float bxB = b[cb];                              // 64,66,68,70 all valid
    float byB = (cb + 1 < 71) ? b[cb + 1] : 0.f;    // 71 is pad
    float w0B = w23[cb];
    float w1B = (cb + 1 < 71) ? w23[cb + 1] : 0.f;  // w23[71] holds bw, NOT a channel
    const char* mA = (const char*)msgA;
    const char* mB = (const char*)msgB;
    unsigned laneOffA = (unsigned)(k << 2);
    unsigned laneOffB = (unsigned)(p << 2);
    for (int node = wid; node < n; node += nwaves) {
        int end = end_off[node];
        int cnt = deg[node];
        int start = end - cnt;
        float ax0 = 0.f, ay0 = 0.f, ax1 = 0.f, ay1 = 0.f;
        float ax2 = 0.f, ay2 = 0.f, ax3 = 0.f, ay3 = 0.f;
        float bxs = 0.f, bys = 0.f;
        for (int base = 0; base < cnt; base += 64) {
            int rem = min(cnt - base, 64);
            int se = (lane < rem) ? csr[start + base + lane] : 0;
            int j = 0;
            // ---- phase A: 4 pairs (8 edges) per step, 4 loads in flight ----
            for (; j + 7 < rem; j += 8) {
                int sa0 = __builtin_amdgcn_readlane(se, j + 0);
                int sb0 = __builtin_amdgcn_readlane(se, j + 1);
                int sa1 = __builtin_amdgcn_readlane(se, j + 2);
                int sb1 = __builtin_amdgcn_readlane(se, j + 3);
                int sa2 = __builtin_amdgcn_readlane(se, j + 4);
                int sb2 = __builtin_amdgcn_readlane(se, j + 5);
                int sa3 = __builtin_amdgcn_readlane(se, j + 6);
                int sb3 = __builtin_amdgcn_readlane(se, j + 7);
                int s0 = (lane < 32) ? sa0 : sb0;
                int s1 = (lane < 32) ? sa1 : sb1;
                int s2 = (lane < 32) ? sa2 : sb2;
                int s3 = (lane < 32) ? sa3 : sb3;
                float2 v0 = __half22float2(*(const __half2*)(mA + (((unsigned)s0 << 7) | laneOffA)));
                float2 v1 = __half22float2(*(const __half2*)(mA + (((unsigned)s1 << 7) | laneOffA)));
                float2 v2 = __half22float2(*(const __half2*)(mA + (((unsigned)s2 << 7) | laneOffA)));
                float2 v3 = __half22float2(*(const __half2*)(mA + (((unsigned)s3 << 7) | laneOffA)));
                ax0 += v0.x; ay0 += v0.y;  ax1 += v1.x; ay1 += v1.y;
                ax2 += v2.x; ay2 += v2.y;  ax3 += v3.x; ay3 += v3.y;
            }
            // ---- single pairs ----
            for (; j + 1 < rem; j += 2) {
                int sa = __builtin_amdgcn_readlane(se, j);
                int sb = __builtin_amdgcn_readlane(se, j + 1);
                int s = (lane < 32) ? sa : sb;
                float2 v = __half22float2(*(const __half2*)(mA + (((unsigned)s << 7) | laneOffA)));
                ax0 += v.x; ay0 += v.y;
            }
            // ---- odd tail: one edge, lanes 0-31 accumulate ----
            if (j < rem) {
                int s = __builtin_amdgcn_readlane(se, j);
                float2 v = __half22float2(*(const __half2*)(mA + (((unsigned)s << 7) | laneOffA)));
                if (lane < 32) { ax0 += v.x; ay0 += v.y; }
            }
            // ---- phase B: 16 edges per load (L2-resident msgB) ----
            for (int t = 0; t < rem; t += 16) {
                int idx = t + (lane >> 2);
                int ss = __shfl(se, (idx < rem) ? idx : (rem - 1));
                float2 v = __half22float2(*(const __half2*)(mB + (((unsigned)ss << 4) | laneOffB)));
                if (idx < rem) { bxs += v.x; bys += v.y; }
            }
        }
        // combine A halves (lane k <-> lane k+32 hold same channels, different edges)
        float axA = (ax0 + ax1) + (ax2 + ax3);
        float ayA = (ay0 + ay1) + (ay2 + ay3);
        axA += __shfl_xor(axA, 32);
        ayA += __shfl_xor(ayA, 32);
        {   // self-loop, channels 0-63
            float2 sv = __half22float2(msgA[(size_t)node * 32 + k]);
            axA += sv.x; ayA += sv.y;
        }
        // combine B slots (16 edge-slots, groups of 4 lanes share a channel pair)
        bxs += __shfl_xor(bxs, 4);  bxs += __shfl_xor(bxs, 8);
        bxs += __shfl_xor(bxs, 16); bxs += __shfl_xor(bxs, 32);
        bys += __shfl_xor(bys, 4);  bys += __shfl_xor(bys, 8);
        bys += __shfl_xor(bys, 16); bys += __shfl_xor(bys, 32);
        {   // self-loop, channels 64-71
            float2 sv = __half22float2(msgB[(size_t)node * 4 + p]);
            bxs += sv.x; bys += sv.y;
        }
        float dv = dinv[node];
        float pa = fmaxf(dv * axA + bxA, 0.f) * w0A + fmaxf(dv * ayA + byA, 0.f) * w1A;
        float pb = fmaxf(dv * bxs + bxB, 0.f) * w0B + fmaxf(dv * bys + byB, 0.f) * w1B;
        float r = ((lane < 32) ? pa : 0.f) + ((lane < 4) ? pb : 0.f);
#pragma unroll
        for (int off = 32; off > 0; off >>= 1) r += __shfl_down(r, off);
        if (lane == 0) g2[node] = dv * r;
    }
}

// ---- scalar gather 1: q[i] = dinv_i * ( dinv_i*(sum g2[src] + g2[i]) + bw ) ----
// 16-lane group per node: coalesced csr, parallel g2 gathers.
__global__ void sgather_q(const float* __restrict__ g2, const int* __restrict__ csr,
                          const int* __restrict__ end_off, const int* __restrict__ deg,
                          const float* __restrict__ dinv, const float* __restrict__ w23,
                          float* __restrict__ q, int n) {
    float bw = w23[71];
    int lane = threadIdx.x & 63;
    int g = lane >> 4, k = lane & 15;
    int wid = (blockIdx.x * blockDim.x + threadIdx.x) >> 6;
    int nw = (gridDim.x * blockDim.x) >> 6;
    for (int i0 = wid * 4; i0 < n; i0 += nw * 4) {
        int i = i0 + g;
        float acc = 0.f;
        float dv = 0.f;
        if (i < n) {
            int end = end_off[i];
            int cnt = deg[i];
            int start = end - cnt;
            dv = dinv[i];
            for (int e = k; e < cnt; e += 16) acc += g2[csr[start + e]];
        }
        acc += __shfl_down(acc, 8, 16);
        acc += __shfl_down(acc, 4, 16);
        acc += __shfl_down(acc, 2, 16);
        acc += __shfl_down(acc, 1, 16);
        if (i < n && k == 0) q[i] = dv * (dv * (acc + g2[i]) + bw);
    }
}

// ---- scalar gather 2: out[i] = dinv_i*(sum q[src] + q[i]) + b3 ----
__global__ void sgather_out(const float* __restrict__ q, const int* __restrict__ csr,
                            const int* __restrict__ end_off, const int* __restrict__ deg,
                            const float* __restrict__ dinv, const float* __restrict__ b3,
                            float* __restrict__ out, int n) {
    float bv = b3[0];
    int lane = threadIdx.x & 63;
    int g = lane >> 4, k = lane & 15;
    int wid = (blockIdx.x * blockDim.x + threadIdx.x) >> 6;
    int nw = (gridDim.x * blockDim.x) >> 6;
    for (int i0 = wid * 4; i0 < n; i0 += nw * 4) {
        int i = i0 + g;
        float acc = 0.f;
        float dv = 0.f;
        if (i < n) {
            int end = end_off[i];
            int cnt = deg[i];
            int start = end - cnt;
            dv = dinv[i];
            for (int e = k; e < cnt; e += 16) acc += q[csr[start + e]];
        }
        acc += __shfl_down(acc, 8, 16);
        acc += __shfl_down(acc, 4, 16);
        acc += __shfl_down(acc, 2, 16);
        acc += __shfl_down(acc, 1, 16);
        if (i < n && k == 0) out[i] = dv * (acc + q[i]) + bv;
    }
}

extern "C" void kernel_launch(void* const* d_in, const int* in_sizes, int n_in,
                              void* d_out, int out_size, void* d_ws, size_t ws_size,
                              hipStream_t stream) {
    const float* x  = (const float*)d_in[0];
    const int*   ei = (const int*)d_in[1];
    const float* W1 = (const float*)d_in[2];
    const float* b1 = (const float*)d_in[3];
    const float* W2 = (const float*)d_in[4];
    const float* b2 = (const float*)d_in[5];
    const float* W3 = (const float*)d_in[6];
    const float* b3 = (const float*)d_in[7];
    float* out = (float*)d_out;

    const int n = NNODES;
    const int E = in_sizes[1] / 2;
    const int* src = ei;
    const int* dst = ei + E;

    float* ws     = (float*)d_ws;
    float* dinv   = ws;                        // n f32
    int*   deg_i  = (int*)(ws + n);            // n i32
    int*   offs   = deg_i + n;                 // n i32 (END offsets)
    int*   bcnt   = offs + n;                  // 256 i32
    int*   bstart = bcnt + 256;                // 256 i32
    float* w23    = (float*)(bstart + 256);    // 72 f32 (+ pad to 80)
    __half* Wt    = (__half*)(w23 + 80);       // 80*WT_LD halves (pad to 11008)
    float* g2     = (float*)(Wt + 11008);      // n f32
    float* q      = g2 + n;                    // n f32
    int*   csr    = (int*)(q + n);             // E i32
    __half* msgA  = (__half*)(csr + E + 16);   // +64B pad -> 128B-aligned; n*64 halves (12.8 MB)
    __half* msgB  = msgA + (size_t)n * 64;     // n*8 halves (1.6 MB)
    unsigned* bdata = (unsigned*)(msgB + (size_t)n * 8);  // NB*BCAP u32 (7.2 MB)

    // ---- CSR build ----
    hipMemsetAsync(bcnt, 0, 256 * sizeof(int), stream);
    binA_kernel<<<(E + 4095) / 4096, 256, 0, stream>>>(src, dst, bcnt, bdata, E);
    prep_kernel<<<3, 1024, 0, stream>>>(bcnt, bstart, W2, b2, W3, w23, W1, Wt);
    binB2_kernel<<<NB, 1024, 0, stream>>>(bcnt, bstart, bdata, deg_i, offs, dinv, csr, n);

    // ---- layer 1 transform via MFMA: msgA/msgB = fp16( (x@W1)*dinv ), split channels ----
    xform_mfma<<<1563, 256, 0, stream>>>(x, Wt, dinv, msgA, msgB, n);

    // ---- fused layer-1 gather + ReLU + (W2*W3) contraction -> scalar per node ----
    gather_fused<<<2048, 256, 0, stream>>>((const __half2*)msgA, (const __half2*)msgB,
                                           csr, offs, deg_i, dinv, b1, w23, g2, n);

    // ---- collapsed layers 2+3: two scalar aggregations (16-lane group per node) ----
    sgather_q<<<1024, 256, 0, stream>>>(g2, csr, offs, deg_i, dinv, w23, q, n);
    sgather_out<<<1024, 256, 0, stream>>>(q, csr, offs, deg_i, dinv, b3, out, n);
}

// Round 3
// 225.667 us; speedup vs baseline: 1.0805x; 1.0587x over previous
//
#include <hip/hip_runtime.h>
#include <hip/hip_fp16.h>

#define NNODES 100000
#define NB 196         // coarse buckets: node >> 9 (512 nodes each)
#define BSHIFT 9
#define BMASK 511
#define BCAP 9216      // per-bucket capacity (avg 8163, sigma ~90 -> +11.7 sigma)
#define WT_LD 136      // padded k-stride (halves) for transposed W1

typedef _Float16 half8 __attribute__((ext_vector_type(8)));
typedef float floatx4 __attribute__((ext_vector_type(4)));

// ---- phase A: coarse-bin edges; two LDS atomics/edge (R11-proven shape) ----
__global__ void binA_kernel(const int* __restrict__ src, const int* __restrict__ dst,
                            int* __restrict__ bcnt, unsigned* __restrict__ bdata, int E) {
    __shared__ int hist[NB];
    __shared__ int gb[NB];
    __shared__ int cur[NB];
    const int BATCH = 4096;  // 16 edges / thread
    for (int base = blockIdx.x * BATCH; base < E; base += gridDim.x * BATCH) {
        for (int i = threadIdx.x; i < NB; i += blockDim.x) hist[i] = 0;
        __syncthreads();
        int s[16], d[16];
        int cnt = 0;
        if (base + BATCH <= E) {  // full batch: int4 loads
#pragma unroll
            for (int q = 0; q < 4; ++q) {
                int4 sv = ((const int4*)(src + base))[q * 256 + threadIdx.x];
                int4 dv = ((const int4*)(dst + base))[q * 256 + threadIdx.x];
                s[cnt] = sv.x; d[cnt] = dv.x; atomicAdd(&hist[dv.x >> BSHIFT], 1); ++cnt;
                s[cnt] = sv.y; d[cnt] = dv.y; atomicAdd(&hist[dv.y >> BSHIFT], 1); ++cnt;
                s[cnt] = sv.z; d[cnt] = dv.z; atomicAdd(&hist[dv.z >> BSHIFT], 1); ++cnt;
                s[cnt] = sv.w; d[cnt] = dv.w; atomicAdd(&hist[dv.w >> BSHIFT], 1); ++cnt;
            }
        } else {
#pragma unroll
            for (int k = 0; k < 16; ++k) {
                int idx = base + k * 256 + threadIdx.x;
                if (idx < E) {
                    s[cnt] = src[idx];
                    d[cnt] = dst[idx];
                    atomicAdd(&hist[d[cnt] >> BSHIFT], 1);
                    ++cnt;
                }
            }
        }
        __syncthreads();
        for (int i = threadIdx.x; i < NB; i += blockDim.x) {
            int c = hist[i];
            gb[i] = (c > 0) ? atomicAdd(&bcnt[i], c) : 0;
            cur[i] = 0;
        }
        __syncthreads();
        for (int k = 0; k < cnt; ++k) {
            int b = d[k] >> BSHIFT;
            int lo = gb[b] + atomicAdd(&cur[b], 1);
            if (lo < BCAP)
                bdata[(size_t)b * BCAP + lo] = ((unsigned)s[k] << BSHIFT) | ((unsigned)d[k] & BMASK);
        }
        __syncthreads();
    }
}

// ---- fused prep: block 0 = bucket scan, block 1 = w23 fold, block 2 = W1 transpose/fp16 ----
__global__ __launch_bounds__(1024) void prep_kernel(
        const int* __restrict__ bcnt, int* __restrict__ bstart,
        const float* __restrict__ W2, const float* __restrict__ b2,
        const float* __restrict__ W3, float* __restrict__ w23,
        const float* __restrict__ W1, __half* __restrict__ Wt) {
    if (blockIdx.x == 0) {
        __shared__ int sh[NB];
        int t = threadIdx.x;
        if (t < NB) sh[t] = min(bcnt[t], BCAP);
        __syncthreads();
        if (t == 0) {
            int acc = 0;
            for (int i = 0; i < NB; ++i) { int v = sh[i]; sh[i] = acc; acc += v; }
        }
        __syncthreads();
        if (t < NB) bstart[t] = sh[t];
    } else if (blockIdx.x == 1) {
        int k = threadIdx.x;
        if (k < 71) {
            float a = 0.f;
            for (int j = 0; j < 82; ++j) a += W2[k * 82 + j] * W3[j];
            w23[k] = a;
        } else if (k == 71) {
            float a = 0.f;
            for (int j = 0; j < 82; ++j) a += b2[j] * W3[j];
            w23[71] = a;
        }
    } else {
        for (int i = threadIdx.x; i < 80 * WT_LD; i += blockDim.x) {
            int nn = i / WT_LD, k = i - nn * WT_LD;
            float v = (nn < 71 && k < 128) ? W1[k * 71 + nn] : 0.f;
            Wt[i] = __float2half(v);
        }
    }
}

// ---- phase B: per-bucket (512 nodes) LDS-cached hist + scan + CSR fill (R11 shape) ----
__global__ __launch_bounds__(1024) void binB2_kernel(
        const int* __restrict__ bcnt, const int* __restrict__ bstart,
        const unsigned* __restrict__ bdata,
        int* __restrict__ deg, int* __restrict__ end_off, float* __restrict__ dinv,
        int* __restrict__ csr, int n) {
    __shared__ unsigned edata[BCAP];   // 36 KB: bucket cached in LDS
    __shared__ int hist[512];
    __shared__ int cur[512];
    __shared__ int wsum[8];
    int b = blockIdx.x;
    int tid = threadIdx.x;
    int cnt = min(bcnt[b], BCAP);
    int base = bstart[b];
    const unsigned* p = bdata + (size_t)b * BCAP;
    if (tid < 512) hist[tid] = 0;
    __syncthreads();
    for (int i = tid; i < cnt; i += 1024) {
        unsigned e = p[i];
        edata[i] = e;
        atomicAdd(&hist[e & BMASK], 1);
    }
    __syncthreads();
    if (tid < 512) {  // 8-wave inclusive scan of hist
        int v = hist[tid];
        int lane = tid & 63;
        int incl = v;
#pragma unroll
        for (int off = 1; off < 64; off <<= 1) {
            int t = __shfl_up(incl, off);
            if (lane >= off) incl += t;
        }
        cur[tid] = incl;  // stash inclusive intra-wave prefix
        if (lane == 63) wsum[tid >> 6] = incl;
    }
    __syncthreads();
    if (tid == 0) {
        int acc = 0;
#pragma unroll
        for (int w = 0; w < 8; ++w) { int t = wsum[w]; wsum[w] = acc; acc += t; }
    }
    __syncthreads();
    if (tid < 512) {
        int v = hist[tid];
        int start = base + wsum[tid >> 6] + cur[tid] - v;  // exclusive prefix
        int node = (b << BSHIFT) + tid;
        if (node < n) {
            deg[node] = v;
            end_off[node] = start + v;
            dinv[node] = rsqrtf((float)v + 1.0f);
        }
        cur[tid] = start;
    }
    __syncthreads();
    for (int i = tid; i < cnt; i += 1024) {
        unsigned e = edata[i];
        int pos = atomicAdd(&cur[e & BMASK], 1);
        csr[pos] = (int)(e >> BSHIFT);
    }
}

// ---- MFMA transform: split-channel output ----
// msgA[row][0..63] (128B rows, 2 aligned lines), msgB[row][0..7] (chs 64..71, 16B rows)
__global__ __launch_bounds__(256) void xform_mfma(
        const float* __restrict__ x, const __half* __restrict__ Wt,
        const float* __restrict__ scale, __half* __restrict__ msgA,
        __half* __restrict__ msgB, int n) {
    __shared__ __half Wsh[80 * WT_LD];   // 21.25 KB
    {
        const uint4* sp = (const uint4*)Wt;
        uint4* dp = (uint4*)Wsh;
        for (int i = threadIdx.x; i < (80 * WT_LD * 2) / 16; i += blockDim.x) dp[i] = sp[i];
    }
    __syncthreads();
    int lane = threadIdx.x & 63;
    int m = lane & 15, q = lane >> 4;
    int gw = (blockIdx.x * blockDim.x + threadIdx.x) >> 6;
    int nw = (gridDim.x * blockDim.x) >> 6;
    int nrt = n >> 4;  // 16-row tiles (n % 16 == 0)
    for (int rt = gw; rt < nrt; rt += nw) {
        int rb = rt << 4;
        const float* xr = x + (size_t)(rb + m) * 128 + q * 8;
        floatx4 acc[5];
#pragma unroll
        for (int t = 0; t < 5; ++t) acc[t] = (floatx4){0.f, 0.f, 0.f, 0.f};
#pragma unroll
        for (int ks = 0; ks < 4; ++ks) {
            float4 f0 = *(const float4*)(xr + ks * 32);
            float4 f1 = *(const float4*)(xr + ks * 32 + 4);
            half8 a;
            a[0] = (_Float16)f0.x; a[1] = (_Float16)f0.y;
            a[2] = (_Float16)f0.z; a[3] = (_Float16)f0.w;
            a[4] = (_Float16)f1.x; a[5] = (_Float16)f1.y;
            a[6] = (_Float16)f1.z; a[7] = (_Float16)f1.w;
#pragma unroll
            for (int t = 0; t < 5; ++t) {
                half8 b = *(const half8*)&Wsh[(t * 16 + m) * WT_LD + ks * 32 + q * 8];
                acc[t] = __builtin_amdgcn_mfma_f32_16x16x32_f16(a, b, acc[t], 0, 0, 0);
            }
        }
        float sc[4];
#pragma unroll
        for (int r = 0; r < 4; ++r) sc[r] = scale[rb + q * 4 + r];
#pragma unroll
        for (int t = 0; t < 5; ++t) {
            int col = t * 16 + m;
#pragma unroll
            for (int r = 0; r < 4; ++r) {
                __half hv = __float2half(acc[t][r] * sc[r]);
                int row = rb + q * 4 + r;
                if (t < 4) {
                    msgA[(size_t)row * 64 + col] = hv;
                } else if (m < 8) {
                    msgB[(size_t)row * 8 + m] = hv;   // channels 64..71 (71 = zero pad)
                }
            }
        }
    }
}

// ---- fused gather + ReLU + w23 contraction ----
// R14: 8-lane group per node, 8 nodes per wave. Lane li owns channels 8li..8li+7
// (one dwordx4 = half the msgA row per lane, full row per group per load).
// Self-loop = virtual edge at slot i==deg with idx=node. Per-node cross-lane
// reduction collapses to a 3-round 8-lane scalar reduce. csr prefetched 2 deep.
__global__ __launch_bounds__(256) void gather_fused(
        const __half* __restrict__ msgA, const __half* __restrict__ msgB,
        const int* __restrict__ csr, const int* __restrict__ end_off,
        const int* __restrict__ deg, const float* __restrict__ dinv,
        const float* __restrict__ b, const float* __restrict__ w23,
        float* __restrict__ g2, int n) {
    int lane = threadIdx.x & 63;
    int li = lane & 7;                 // lane within group
    int wid = (blockIdx.x * blockDim.x + threadIdx.x) >> 6;
    int nwaves = (gridDim.x * blockDim.x) >> 6;
    // per-lane channel params: A channels 8li..8li+7, B channel 64+li
    float bA[8], wA[8];
#pragma unroll
    for (int j = 0; j < 8; ++j) { bA[j] = b[8 * li + j]; wA[j] = w23[8 * li + j]; }
    float bB = (li < 7) ? b[64 + li] : 0.f;
    float wB = (li < 7) ? w23[64 + li] : 0.f;      // li==7 is pad channel 71
    const char* mA = (const char*)msgA;
    const char* mB = (const char*)msgB;
    unsigned laneA   = (unsigned)(li << 4);        // byte offset in 128B A row
    unsigned laneBof = (unsigned)((li >> 1) << 2); // dword offset in 16B B row
    unsigned laneBsh = (unsigned)((li & 1) << 4);  // half-select shift
    int ntiles = (n + 7) >> 3;
    for (int tile = wid; tile < ntiles; tile += nwaves) {
        int node = (tile << 3) + (lane >> 3);
        int d = -1, st = 0; float dv = 0.f;
        if (node < n) {
            int e = end_off[node];
            d = deg[node];
            st = e - d;
            dv = dinv[node];
        }
        // wave-max of slot count (group-uniform d; groups differ)
        int tmax = d;
        tmax = max(tmax, __shfl_xor(tmax, 8));
        tmax = max(tmax, __shfl_xor(tmax, 16));
        tmax = max(tmax, __shfl_xor(tmax, 32));
        tmax = __builtin_amdgcn_readfirstlane(tmax);
        float acc[8];
#pragma unroll
        for (int j = 0; j < 8; ++j) acc[j] = 0.f;
        float bsum = 0.f;
        // prefetch csr for slots 0,1 (clamped addresses are always valid)
        int c0 = csr[(0 < d) ? st : 0];
        int c1 = csr[(1 < d) ? st + 1 : 0];
        for (int i = 0; i <= tmax; i += 2) {
            int p0 = csr[(i + 2 < d) ? st + i + 2 : 0];
            int p1 = csr[(i + 3 < d) ? st + i + 3 : 0];
            // slot i
            if (i <= d) {
                unsigned idx = (unsigned)((i < d) ? c0 : node);
                half8 row = *(const half8*)(mA + ((idx << 7) | laneA));
                unsigned bw = *(const unsigned*)(mB + ((idx << 4) | laneBof));
#pragma unroll
                for (int j = 0; j < 8; ++j) acc[j] += (float)row[j];
                unsigned short us = (unsigned short)(bw >> laneBsh);
                _Float16 hf;
                __builtin_memcpy(&hf, &us, 2);
                bsum += (float)hf;
            }
            // slot i+1
            if (i + 1 <= d) {
                unsigned idx = (unsigned)((i + 1 < d) ? c1 : node);
                half8 row = *(const half8*)(mA + ((idx << 7) | laneA));
                unsigned bw = *(const unsigned*)(mB + ((idx << 4) | laneBof));
#pragma unroll
                for (int j = 0; j < 8; ++j) acc[j] += (float)row[j];
                unsigned short us = (unsigned short)(bw >> laneBsh);
                _Float16 hf;
                __builtin_memcpy(&hf, &us, 2);
                bsum += (float)hf;
            }
            c0 = p0;
            c1 = p1;
        }
        float p = 0.f;
#pragma unroll
        for (int j = 0; j < 8; ++j) p += fmaxf(dv * acc[j] + bA[j], 0.f) * wA[j];
        p += fmaxf(dv * bsum + bB, 0.f) * wB;
        p += __shfl_xor(p, 1);
        p += __shfl_xor(p, 2);
        p += __shfl_xor(p, 4);
        if (node < n && li == 0) g2[node] = dv * p;
    }
}

// ---- scalar gather 1: q[i] = dinv_i * ( dinv_i*(sum g2[src] + g2[i]) + bw ) ----
// 16-lane group per node: coalesced csr, parallel g2 gathers.
__global__ void sgather_q(const float* __restrict__ g2, const int* __restrict__ csr,
                          const int* __restrict__ end_off, const int* __restrict__ deg,
                          const float* __restrict__ dinv, const float* __restrict__ w23,
                          float* __restrict__ q, int n) {
    float bw = w23[71];
    int lane = threadIdx.x & 63;
    int g = lane >> 4, k = lane & 15;
    int wid = (blockIdx.x * blockDim.x + threadIdx.x) >> 6;
    int nw = (gridDim.x * blockDim.x) >> 6;
    for (int i0 = wid * 4; i0 < n; i0 += nw * 4) {
        int i = i0 + g;
        float acc = 0.f;
        float dv = 0.f;
        if (i < n) {
            int end = end_off[i];
            int cnt = deg[i];
            int start = end - cnt;
            dv = dinv[i];
            for (int e = k; e < cnt; e += 16) acc += g2[csr[start + e]];
        }
        acc += __shfl_down(acc, 8, 16);
        acc += __shfl_down(acc, 4, 16);
        acc += __shfl_down(acc, 2, 16);
        acc += __shfl_down(acc, 1, 16);
        if (i < n && k == 0) q[i] = dv * (dv * (acc + g2[i]) + bw);
    }
}

// ---- scalar gather 2: out[i] = dinv_i*(sum q[src] + q[i]) + b3 ----
__global__ void sgather_out(const float* __restrict__ q, const int* __restrict__ csr,
                            const int* __restrict__ end_off, const int* __restrict__ deg,
                            const float* __restrict__ dinv, const float* __restrict__ b3,
                            float* __restrict__ out, int n) {
    float bv = b3[0];
    int lane = threadIdx.x & 63;
    int g = lane >> 4, k = lane & 15;
    int wid = (blockIdx.x * blockDim.x + threadIdx.x) >> 6;
    int nw = (gridDim.x * blockDim.x) >> 6;
    for (int i0 = wid * 4; i0 < n; i0 += nw * 4) {
        int i = i0 + g;
        float acc = 0.f;
        float dv = 0.f;
        if (i < n) {
            int end = end_off[i];
            int cnt = deg[i];
            int start = end - cnt;
            dv = dinv[i];
            for (int e = k; e < cnt; e += 16) acc += q[csr[start + e]];
        }
        acc += __shfl_down(acc, 8, 16);
        acc += __shfl_down(acc, 4, 16);
        acc += __shfl_down(acc, 2, 16);
        acc += __shfl_down(acc, 1, 16);
        if (i < n && k == 0) out[i] = dv * (acc + q[i]) + bv;
    }
}

extern "C" void kernel_launch(void* const* d_in, const int* in_sizes, int n_in,
                              void* d_out, int out_size, void* d_ws, size_t ws_size,
                              hipStream_t stream) {
    const float* x  = (const float*)d_in[0];
    const int*   ei = (const int*)d_in[1];
    const float* W1 = (const float*)d_in[2];
    const float* b1 = (const float*)d_in[3];
    const float* W2 = (const float*)d_in[4];
    const float* b2 = (const float*)d_in[5];
    const float* W3 = (const float*)d_in[6];
    const float* b3 = (const float*)d_in[7];
    float* out = (float*)d_out;

    const int n = NNODES;
    const int E = in_sizes[1] / 2;
    const int* src = ei;
    const int* dst = ei + E;

    float* ws     = (float*)d_ws;
    float* dinv   = ws;                        // n f32
    int*   deg_i  = (int*)(ws + n);            // n i32
    int*   offs   = deg_i + n;                 // n i32 (END offsets)
    int*   bcnt   = offs + n;                  // 256 i32
    int*   bstart = bcnt + 256;                // 256 i32
    float* w23    = (float*)(bstart + 256);    // 72 f32 (+ pad to 80)
    __half* Wt    = (__half*)(w23 + 80);       // 80*WT_LD halves (pad to 11008)
    float* g2     = (float*)(Wt + 11008);      // n f32
    float* q      = g2 + n;                    // n f32
    int*   csr    = (int*)(q + n);             // E i32
    __half* msgA  = (__half*)(csr + E + 16);   // +64B pad -> 128B-aligned; n*64 halves (12.8 MB)
    __half* msgB  = msgA + (size_t)n * 64;     // n*8 halves (1.6 MB)
    unsigned* bdata = (unsigned*)(msgB + (size_t)n * 8);  // NB*BCAP u32 (7.2 MB)

    // ---- CSR build ----
    hipMemsetAsync(bcnt, 0, 256 * sizeof(int), stream);
    binA_kernel<<<(E + 4095) / 4096, 256, 0, stream>>>(src, dst, bcnt, bdata, E);
    prep_kernel<<<3, 1024, 0, stream>>>(bcnt, bstart, W2, b2, W3, w23, W1, Wt);
    binB2_kernel<<<NB, 1024, 0, stream>>>(bcnt, bstart, bdata, deg_i, offs, dinv, csr, n);

    // ---- layer 1 transform via MFMA: msgA/msgB = fp16( (x@W1)*dinv ), split channels ----
    xform_mfma<<<1563, 256, 0, stream>>>(x, Wt, dinv, msgA, msgB, n);

    // ---- fused layer-1 gather + ReLU + (W2*W3) contraction -> scalar per node ----
    // 1563 blocks = 6252 waves; 12500 tiles of 8 nodes -> 2 tiles/wave, uniform.
    gather_fused<<<1563, 256, 0, stream>>>(msgA, msgB, csr, offs, deg_i, dinv, b1, w23, g2, n);

    // ---- collapsed layers 2+3: two scalar aggregations (16-lane group per node) ----
    sgather_q<<<1024, 256, 0, stream>>>(g2, csr, offs, deg_i, dinv, w23, q, n);
    sgather_out<<<1024, 256, 0, stream>>>(q, csr, offs, deg_i, dinv, b3, out, n);
}

// Round 4
// 212.466 us; speedup vs baseline: 1.1476x; 1.0621x over previous
//
#include <hip/hip_runtime.h>
#include <hip/hip_fp16.h>

#define NNODES 100000
#define NB 196         // coarse buckets: node >> 9 (512 nodes each)
#define BSHIFT 9
#define BMASK 511
#define BCAP 9216      // per-bucket capacity (avg 8163, sigma ~90 -> +11.7 sigma)
#define WT_LD 136      // padded k-stride (halves) for transposed W1

typedef _Float16 half8 __attribute__((ext_vector_type(8)));
typedef float floatx4 __attribute__((ext_vector_type(4)));

// ---- phase A: coarse-bin edges; two LDS atomics/edge (R11-proven shape) ----
__global__ void binA_kernel(const int* __restrict__ src, const int* __restrict__ dst,
                            int* __restrict__ bcnt, unsigned* __restrict__ bdata, int E) {
    __shared__ int hist[NB];
    __shared__ int gb[NB];
    __shared__ int cur[NB];
    const int BATCH = 4096;  // 16 edges / thread
    for (int base = blockIdx.x * BATCH; base < E; base += gridDim.x * BATCH) {
        for (int i = threadIdx.x; i < NB; i += blockDim.x) hist[i] = 0;
        __syncthreads();
        int s[16], d[16];
        int cnt = 0;
        if (base + BATCH <= E) {  // full batch: int4 loads
#pragma unroll
            for (int q = 0; q < 4; ++q) {
                int4 sv = ((const int4*)(src + base))[q * 256 + threadIdx.x];
                int4 dv = ((const int4*)(dst + base))[q * 256 + threadIdx.x];
                s[cnt] = sv.x; d[cnt] = dv.x; atomicAdd(&hist[dv.x >> BSHIFT], 1); ++cnt;
                s[cnt] = sv.y; d[cnt] = dv.y; atomicAdd(&hist[dv.y >> BSHIFT], 1); ++cnt;
                s[cnt] = sv.z; d[cnt] = dv.z; atomicAdd(&hist[dv.z >> BSHIFT], 1); ++cnt;
                s[cnt] = sv.w; d[cnt] = dv.w; atomicAdd(&hist[dv.w >> BSHIFT], 1); ++cnt;
            }
        } else {
#pragma unroll
            for (int k = 0; k < 16; ++k) {
                int idx = base + k * 256 + threadIdx.x;
                if (idx < E) {
                    s[cnt] = src[idx];
                    d[cnt] = dst[idx];
                    atomicAdd(&hist[d[cnt] >> BSHIFT], 1);
                    ++cnt;
                }
            }
        }
        __syncthreads();
        for (int i = threadIdx.x; i < NB; i += blockDim.x) {
            int c = hist[i];
            gb[i] = (c > 0) ? atomicAdd(&bcnt[i], c) : 0;
            cur[i] = 0;
        }
        __syncthreads();
        for (int k = 0; k < cnt; ++k) {
            int b = d[k] >> BSHIFT;
            int lo = gb[b] + atomicAdd(&cur[b], 1);
            if (lo < BCAP)
                bdata[(size_t)b * BCAP + lo] = ((unsigned)s[k] << BSHIFT) | ((unsigned)d[k] & BMASK);
        }
        __syncthreads();
    }
}

// ---- fused prep: block 0 = bucket scan, block 1 = w23 fold, block 2 = W1 transpose/fp16 ----
__global__ __launch_bounds__(1024) void prep_kernel(
        const int* __restrict__ bcnt, int* __restrict__ bstart,
        const float* __restrict__ W2, const float* __restrict__ b2,
        const float* __restrict__ W3, float* __restrict__ w23,
        const float* __restrict__ W1, __half* __restrict__ Wt) {
    if (blockIdx.x == 0) {
        __shared__ int sh[NB];
        int t = threadIdx.x;
        if (t < NB) sh[t] = min(bcnt[t], BCAP);
        __syncthreads();
        if (t == 0) {
            int acc = 0;
            for (int i = 0; i < NB; ++i) { int v = sh[i]; sh[i] = acc; acc += v; }
        }
        __syncthreads();
        if (t < NB) bstart[t] = sh[t];
    } else if (blockIdx.x == 1) {
        int k = threadIdx.x;
        if (k < 71) {
            float a = 0.f;
            for (int j = 0; j < 82; ++j) a += W2[k * 82 + j] * W3[j];
            w23[k] = a;
        } else if (k == 71) {
            float a = 0.f;
            for (int j = 0; j < 82; ++j) a += b2[j] * W3[j];
            w23[71] = a;
        }
    } else {
        for (int i = threadIdx.x; i < 80 * WT_LD; i += blockDim.x) {
            int nn = i / WT_LD, k = i - nn * WT_LD;
            float v = (nn < 71 && k < 128) ? W1[k * 71 + nn] : 0.f;
            Wt[i] = __float2half(v);
        }
    }
}

// ---- phase B: per-bucket (512 nodes) LDS-cached hist + scan + CSR fill (R11 shape) ----
__global__ __launch_bounds__(1024) void binB2_kernel(
        const int* __restrict__ bcnt, const int* __restrict__ bstart,
        const unsigned* __restrict__ bdata,
        int* __restrict__ deg, int* __restrict__ end_off, float* __restrict__ dinv,
        int* __restrict__ csr, int n) {
    __shared__ unsigned edata[BCAP];   // 36 KB: bucket cached in LDS
    __shared__ int hist[512];
    __shared__ int cur[512];
    __shared__ int wsum[8];
    int b = blockIdx.x;
    int tid = threadIdx.x;
    int cnt = min(bcnt[b], BCAP);
    int base = bstart[b];
    const unsigned* p = bdata + (size_t)b * BCAP;
    if (tid < 512) hist[tid] = 0;
    __syncthreads();
    for (int i = tid; i < cnt; i += 1024) {
        unsigned e = p[i];
        edata[i] = e;
        atomicAdd(&hist[e & BMASK], 1);
    }
    __syncthreads();
    if (tid < 512) {  // 8-wave inclusive scan of hist
        int v = hist[tid];
        int lane = tid & 63;
        int incl = v;
#pragma unroll
        for (int off = 1; off < 64; off <<= 1) {
            int t = __shfl_up(incl, off);
            if (lane >= off) incl += t;
        }
        cur[tid] = incl;  // stash inclusive intra-wave prefix
        if (lane == 63) wsum[tid >> 6] = incl;
    }
    __syncthreads();
    if (tid == 0) {
        int acc = 0;
#pragma unroll
        for (int w = 0; w < 8; ++w) { int t = wsum[w]; wsum[w] = acc; acc += t; }
    }
    __syncthreads();
    if (tid < 512) {
        int v = hist[tid];
        int start = base + wsum[tid >> 6] + cur[tid] - v;  // exclusive prefix
        int node = (b << BSHIFT) + tid;
        if (node < n) {
            deg[node] = v;
            end_off[node] = start + v;
            dinv[node] = rsqrtf((float)v + 1.0f);
        }
        cur[tid] = start;
    }
    __syncthreads();
    for (int i = tid; i < cnt; i += 1024) {
        unsigned e = edata[i];
        int pos = atomicAdd(&cur[e & BMASK], 1);
        csr[pos] = (int)(e >> BSHIFT);
    }
}

// ---- MFMA transform: split-channel output ----
// msgA[row][0..63] (128B rows, 2 aligned lines), msgB[row][0..7] (chs 64..71, 16B rows)
__global__ __launch_bounds__(256) void xform_mfma(
        const float* __restrict__ x, const __half* __restrict__ Wt,
        const float* __restrict__ scale, __half* __restrict__ msgA,
        __half* __restrict__ msgB, int n) {
    __shared__ __half Wsh[80 * WT_LD];   // 21.25 KB
    {
        const uint4* sp = (const uint4*)Wt;
        uint4* dp = (uint4*)Wsh;
        for (int i = threadIdx.x; i < (80 * WT_LD * 2) / 16; i += blockDim.x) dp[i] = sp[i];
    }
    __syncthreads();
    int lane = threadIdx.x & 63;
    int m = lane & 15, q = lane >> 4;
    int gw = (blockIdx.x * blockDim.x + threadIdx.x) >> 6;
    int nw = (gridDim.x * blockDim.x) >> 6;
    int nrt = n >> 4;  // 16-row tiles (n % 16 == 0)
    for (int rt = gw; rt < nrt; rt += nw) {
        int rb = rt << 4;
        const float* xr = x + (size_t)(rb + m) * 128 + q * 8;
        floatx4 acc[5];
#pragma unroll
        for (int t = 0; t < 5; ++t) acc[t] = (floatx4){0.f, 0.f, 0.f, 0.f};
#pragma unroll
        for (int ks = 0; ks < 4; ++ks) {
            float4 f0 = *(const float4*)(xr + ks * 32);
            float4 f1 = *(const float4*)(xr + ks * 32 + 4);
            half8 a;
            a[0] = (_Float16)f0.x; a[1] = (_Float16)f0.y;
            a[2] = (_Float16)f0.z; a[3] = (_Float16)f0.w;
            a[4] = (_Float16)f1.x; a[5] = (_Float16)f1.y;
            a[6] = (_Float16)f1.z; a[7] = (_Float16)f1.w;
#pragma unroll
            for (int t = 0; t < 5; ++t) {
                half8 b = *(const half8*)&Wsh[(t * 16 + m) * WT_LD + ks * 32 + q * 8];
                acc[t] = __builtin_amdgcn_mfma_f32_16x16x32_f16(a, b, acc[t], 0, 0, 0);
            }
        }
        float sc[4];
#pragma unroll
        for (int r = 0; r < 4; ++r) sc[r] = scale[rb + q * 4 + r];
#pragma unroll
        for (int t = 0; t < 5; ++t) {
            int col = t * 16 + m;
#pragma unroll
            for (int r = 0; r < 4; ++r) {
                __half hv = __float2half(acc[t][r] * sc[r]);
                int row = rb + q * 4 + r;
                if (t < 4) {
                    msgA[(size_t)row * 64 + col] = hv;
                } else if (m < 8) {
                    msgB[(size_t)row * 8 + m] = hv;   // channels 64..71 (71 = zero pad)
                }
            }
        }
    }
}

// ---- fused gather + ReLU + w23 contraction ----
// R15: 8-lane group per node, 4-slot software pipeline. Rows for slots i+4..i+7
// are ISSUED while slots i..i+3 (loaded one iteration earlier) are accumulated;
// csr prefetched 8 slots ahead. ~12 loads in flight per wave.
// Self-loop = virtual edge at slot i==deg with idx=node.
__global__ __launch_bounds__(256) void gather_fused(
        const __half* __restrict__ msgA, const __half* __restrict__ msgB,
        const int* __restrict__ csr, const int* __restrict__ end_off,
        const int* __restrict__ deg, const float* __restrict__ dinv,
        const float* __restrict__ b, const float* __restrict__ w23,
        float* __restrict__ g2, int n) {
    int lane = threadIdx.x & 63;
    int li = lane & 7;                 // lane within group
    int wid = (blockIdx.x * blockDim.x + threadIdx.x) >> 6;
    int nwaves = (gridDim.x * blockDim.x) >> 6;
    // per-lane channel params: A channels 8li..8li+7, B channel 64+li
    float bA[8], wA[8];
#pragma unroll
    for (int j = 0; j < 8; ++j) { bA[j] = b[8 * li + j]; wA[j] = w23[8 * li + j]; }
    float bB = (li < 7) ? b[64 + li] : 0.f;
    float wB = (li < 7) ? w23[64 + li] : 0.f;      // li==7 is pad channel 71
    const char* mA = (const char*)msgA;
    const char* mB = (const char*)msgB;
    unsigned laneA   = (unsigned)(li << 4);        // byte offset in 128B A row
    unsigned laneBof = (unsigned)((li >> 1) << 2); // dword offset in 16B B row
    unsigned laneBsh = (unsigned)((li & 1) << 4);  // half-select shift
    int ntiles = n >> 3;               // n % 8 == 0 -> all nodes valid
    for (int tile = wid; tile < ntiles; tile += nwaves) {
        int node = (tile << 3) + (lane >> 3);
        int e = end_off[node];
        int d = deg[node];
        int st = e - d;
        float dv = dinv[node];
        // wave-max slot count (self-edge at slot d)
        int tmax = d;
        tmax = max(tmax, __shfl_xor(tmax, 8));
        tmax = max(tmax, __shfl_xor(tmax, 16));
        tmax = max(tmax, __shfl_xor(tmax, 32));
        tmax = __builtin_amdgcn_readfirstlane(tmax);
        float acc[8];
#pragma unroll
        for (int j = 0; j < 8; ++j) acc[j] = 0.f;
        float bsum = 0.f;
        // ---- prologue: csr slots 0..7, rows for slots 0..3 ----
        int c0 = csr[(0 < d) ? st + 0 : 0];
        int c1 = csr[(1 < d) ? st + 1 : 0];
        int c2 = csr[(2 < d) ? st + 2 : 0];
        int c3 = csr[(3 < d) ? st + 3 : 0];
        int c4 = csr[(4 < d) ? st + 4 : 0];
        int c5 = csr[(5 < d) ? st + 5 : 0];
        int c6 = csr[(6 < d) ? st + 6 : 0];
        int c7 = csr[(7 < d) ? st + 7 : 0];
        unsigned i0 = (unsigned)((0 < d) ? c0 : node);
        unsigned i1 = (unsigned)((1 < d) ? c1 : node);
        unsigned i2 = (unsigned)((2 < d) ? c2 : node);
        unsigned i3 = (unsigned)((3 < d) ? c3 : node);
        half8 r0 = *(const half8*)(mA + ((i0 << 7) | laneA));
        half8 r1 = *(const half8*)(mA + ((i1 << 7) | laneA));
        half8 r2 = *(const half8*)(mA + ((i2 << 7) | laneA));
        half8 r3 = *(const half8*)(mA + ((i3 << 7) | laneA));
        unsigned w0 = *(const unsigned*)(mB + ((i0 << 4) | laneBof));
        unsigned w1 = *(const unsigned*)(mB + ((i1 << 4) | laneBof));
        unsigned w2 = *(const unsigned*)(mB + ((i2 << 4) | laneBof));
        unsigned w3 = *(const unsigned*)(mB + ((i3 << 4) | laneBof));
        for (int i = 0; i <= tmax; i += 4) {
            // prefetch csr slots i+8..i+11
            int n0 = csr[(i + 8  < d) ? st + i + 8  : 0];
            int n1 = csr[(i + 9  < d) ? st + i + 9  : 0];
            int n2 = csr[(i + 10 < d) ? st + i + 10 : 0];
            int n3 = csr[(i + 11 < d) ? st + i + 11 : 0];
            // issue rows for slots i+4..i+7
            unsigned j0 = (unsigned)((i + 4 < d) ? c4 : node);
            unsigned j1 = (unsigned)((i + 5 < d) ? c5 : node);
            unsigned j2 = (unsigned)((i + 6 < d) ? c6 : node);
            unsigned j3 = (unsigned)((i + 7 < d) ? c7 : node);
            half8 s0 = *(const half8*)(mA + ((j0 << 7) | laneA));
            half8 s1 = *(const half8*)(mA + ((j1 << 7) | laneA));
            half8 s2 = *(const half8*)(mA + ((j2 << 7) | laneA));
            half8 s3 = *(const half8*)(mA + ((j3 << 7) | laneA));
            unsigned u0 = *(const unsigned*)(mB + ((j0 << 4) | laneBof));
            unsigned u1 = *(const unsigned*)(mB + ((j1 << 4) | laneBof));
            unsigned u2 = *(const unsigned*)(mB + ((j2 << 4) | laneBof));
            unsigned u3 = *(const unsigned*)(mB + ((j3 << 4) | laneBof));
            // accumulate slots i..i+3 (loaded last iteration)
            if (i <= d) {
#pragma unroll
                for (int j = 0; j < 8; ++j) acc[j] += (float)r0[j];
                unsigned short us = (unsigned short)(w0 >> laneBsh);
                _Float16 hf; __builtin_memcpy(&hf, &us, 2);
                bsum += (float)hf;
            }
            if (i + 1 <= d) {
#pragma unroll
                for (int j = 0; j < 8; ++j) acc[j] += (float)r1[j];
                unsigned short us = (unsigned short)(w1 >> laneBsh);
                _Float16 hf; __builtin_memcpy(&hf, &us, 2);
                bsum += (float)hf;
            }
            if (i + 2 <= d) {
#pragma unroll
                for (int j = 0; j < 8; ++j) acc[j] += (float)r2[j];
                unsigned short us = (unsigned short)(w2 >> laneBsh);
                _Float16 hf; __builtin_memcpy(&hf, &us, 2);
                bsum += (float)hf;
            }
            if (i + 3 <= d) {
#pragma unroll
                for (int j = 0; j < 8; ++j) acc[j] += (float)r3[j];
                unsigned short us = (unsigned short)(w3 >> laneBsh);
                _Float16 hf; __builtin_memcpy(&hf, &us, 2);
                bsum += (float)hf;
            }
            // rotate pipeline
            c4 = n0; c5 = n1; c6 = n2; c7 = n3;
            r0 = s0; r1 = s1; r2 = s2; r3 = s3;
            w0 = u0; w1 = u1; w2 = u2; w3 = u3;
        }
        float p = 0.f;
#pragma unroll
        for (int j = 0; j < 8; ++j) p += fmaxf(dv * acc[j] + bA[j], 0.f) * wA[j];
        p += fmaxf(dv * bsum + bB, 0.f) * wB;
        p += __shfl_xor(p, 1);
        p += __shfl_xor(p, 2);
        p += __shfl_xor(p, 4);
        if (li == 0) g2[node] = dv * p;
    }
}

// ---- scalar gather 1: q[i] = dinv_i * ( dinv_i*(sum g2[src] + g2[i]) + bw ) ----
// 16-lane group per node; 2-deep load unroll for MLP.
__global__ void sgather_q(const float* __restrict__ g2, const int* __restrict__ csr,
                          const int* __restrict__ end_off, const int* __restrict__ deg,
                          const float* __restrict__ dinv, const float* __restrict__ w23,
                          float* __restrict__ q, int n) {
    float bw = w23[71];
    int lane = threadIdx.x & 63;
    int g = lane >> 4, k = lane & 15;
    int wid = (blockIdx.x * blockDim.x + threadIdx.x) >> 6;
    int nw = (gridDim.x * blockDim.x) >> 6;
    for (int i0 = wid * 4; i0 < n; i0 += nw * 4) {
        int i = i0 + g;
        float acc = 0.f;
        float dv = 0.f;
        if (i < n) {
            int end = end_off[i];
            int cnt = deg[i];
            int start = end - cnt;
            dv = dinv[i];
            int e = k;
            for (; e + 16 < cnt; e += 32) {
                int a0 = csr[start + e];
                int a1 = csr[start + e + 16];
                acc += g2[a0] + g2[a1];
            }
            for (; e < cnt; e += 16) acc += g2[csr[start + e]];
        }
        acc += __shfl_down(acc, 8, 16);
        acc += __shfl_down(acc, 4, 16);
        acc += __shfl_down(acc, 2, 16);
        acc += __shfl_down(acc, 1, 16);
        if (i < n && k == 0) q[i] = dv * (dv * (acc + g2[i]) + bw);
    }
}

// ---- scalar gather 2: out[i] = dinv_i*(sum q[src] + q[i]) + b3 ----
__global__ void sgather_out(const float* __restrict__ q, const int* __restrict__ csr,
                            const int* __restrict__ end_off, const int* __restrict__ deg,
                            const float* __restrict__ dinv, const float* __restrict__ b3,
                            float* __restrict__ out, int n) {
    float bv = b3[0];
    int lane = threadIdx.x & 63;
    int g = lane >> 4, k = lane & 15;
    int wid = (blockIdx.x * blockDim.x + threadIdx.x) >> 6;
    int nw = (gridDim.x * blockDim.x) >> 6;
    for (int i0 = wid * 4; i0 < n; i0 += nw * 4) {
        int i = i0 + g;
        float acc = 0.f;
        float dv = 0.f;
        if (i < n) {
            int end = end_off[i];
            int cnt = deg[i];
            int start = end - cnt;
            dv = dinv[i];
            int e = k;
            for (; e + 16 < cnt; e += 32) {
                int a0 = csr[start + e];
                int a1 = csr[start + e + 16];
                acc += q[a0] + q[a1];
            }
            for (; e < cnt; e += 16) acc += q[csr[start + e]];
        }
        acc += __shfl_down(acc, 8, 16);
        acc += __shfl_down(acc, 4, 16);
        acc += __shfl_down(acc, 2, 16);
        acc += __shfl_down(acc, 1, 16);
        if (i < n && k == 0) out[i] = dv * (acc + q[i]) + bv;
    }
}

extern "C" void kernel_launch(void* const* d_in, const int* in_sizes, int n_in,
                              void* d_out, int out_size, void* d_ws, size_t ws_size,
                              hipStream_t stream) {
    const float* x  = (const float*)d_in[0];
    const int*   ei = (const int*)d_in[1];
    const float* W1 = (const float*)d_in[2];
    const float* b1 = (const float*)d_in[3];
    const float* W2 = (const float*)d_in[4];
    const float* b2 = (const float*)d_in[5];
    const float* W3 = (const float*)d_in[6];
    const float* b3 = (const float*)d_in[7];
    float* out = (float*)d_out;

    const int n = NNODES;
    const int E = in_sizes[1] / 2;
    const int* src = ei;
    const int* dst = ei + E;

    float* ws     = (float*)d_ws;
    float* dinv   = ws;                        // n f32
    int*   deg_i  = (int*)(ws + n);            // n i32
    int*   offs   = deg_i + n;                 // n i32 (END offsets)
    int*   bcnt   = offs + n;                  // 256 i32
    int*   bstart = bcnt + 256;                // 256 i32
    float* w23    = (float*)(bstart + 256);    // 72 f32 (+ pad to 80)
    __half* Wt    = (__half*)(w23 + 80);       // 80*WT_LD halves (pad to 11008)
    float* g2     = (float*)(Wt + 11008);      // n f32
    float* q      = g2 + n;                    // n f32
    int*   csr    = (int*)(q + n);             // E i32
    __half* msgA  = (__half*)(csr + E + 16);   // +64B pad -> 128B-aligned; n*64 halves (12.8 MB)
    __half* msgB  = msgA + (size_t)n * 64;     // n*8 halves (1.6 MB)
    unsigned* bdata = (unsigned*)(msgB + (size_t)n * 8);  // NB*BCAP u32 (7.2 MB)

    // ---- CSR build ----
    hipMemsetAsync(bcnt, 0, 256 * sizeof(int), stream);
    binA_kernel<<<(E + 4095) / 4096, 256, 0, stream>>>(src, dst, bcnt, bdata, E);
    prep_kernel<<<3, 1024, 0, stream>>>(bcnt, bstart, W2, b2, W3, w23, W1, Wt);
    binB2_kernel<<<NB, 1024, 0, stream>>>(bcnt, bstart, bdata, deg_i, offs, dinv, csr, n);

    // ---- layer 1 transform via MFMA: msgA/msgB = fp16( (x@W1)*dinv ), split channels ----
    xform_mfma<<<1563, 256, 0, stream>>>(x, Wt, dinv, msgA, msgB, n);

    // ---- fused layer-1 gather + ReLU + (W2*W3) contraction -> scalar per node ----
    // 3125 blocks = 12500 waves = 1 tile (8 nodes) per wave.
    gather_fused<<<3125, 256, 0, stream>>>(msgA, msgB, csr, offs, deg_i, dinv, b1, w23, g2, n);

    // ---- collapsed layers 2+3: two scalar aggregations (16-lane group per node) ----
    sgather_q<<<2048, 256, 0, stream>>>(g2, csr, offs, deg_i, dinv, w23, q, n);
    sgather_out<<<2048, 256, 0, stream>>>(q, csr, offs, deg_i, dinv, b3, out, n);
}